// Round 4
// baseline (72.791 us; speedup 1.0000x reference)
//
#include <hip/hip_runtime.h>

#define HW 9216
#define W 96
#define H 96
#define NC 256
#define NT 49
#define EPSV 1e-5f

#define TSX 16
#define TSY 16          // rows per block tile; each thread owns 2 rows
#define HSZ 22
#define CC 8
#define NZ (NC / CC)    // 32 z-blocks

// ---- fused normalize + message passing step, VB=2 vertical blocking --------
// Block: 128 threads = 16 cols x 8 thread-rows x 2 pixels/thread.
// LDS: xs4[g][hy][hx] = float4 of channels [cbase+4g .. +3] at halo (hy,hx).
// One ds_read_b128 row-tap feeds up to 2 pixels x 4 channels = 8 FMAs.
template <int FUSE_CONV>
__global__ __launch_bounds__(128) void step_kernel(const float* __restrict__ x,
                                                   const float* __restrict__ w,
                                                   const float* __restrict__ cw,
                                                   float* __restrict__ y) {
    __shared__ float4 xs4[2][HSZ][HSZ];  // 15488 B
    const int tx = threadIdx.x & 15;
    const int tyl = threadIdx.x >> 4;    // 0..7
    const int bx = blockIdx.x * TSX;
    const int by = blockIdx.y * TSY;
    const int px = bx + tx;
    const int py0 = by + 2 * tyl;        // this thread's two rows: py0, py0+1
    const int p0 = py0 * W + px;
    const int p1 = p0 + W;

    // load + normalize both pixels' 49 weights (static-indexed, stays in VGPRs)
    float wreg[2][NT];
    float s0 = 0.f, s1 = 0.f;
#pragma unroll
    for (int t = 0; t < NT; ++t) {
        wreg[0][t] = w[t * HW + p0]; s0 += wreg[0][t];
        wreg[1][t] = w[t * HW + p1]; s1 += wreg[1][t];
    }
    const float inv0 = 1.f / (s0 + EPSV);
    const float inv1 = 1.f / (s1 + EPSV);
#pragma unroll
    for (int t = 0; t < NT; ++t) { wreg[0][t] *= inv0; wreg[1][t] *= inv1; }

    // stage 8 channels' 22x22 halos as two float4 planes (zero-padded)
    const int cbase = blockIdx.z * CC;
    const float* __restrict__ xb = x + cbase * HW;
    for (int i = threadIdx.x; i < 2 * HSZ * HSZ; i += 128) {
        int g = (i >= HSZ * HSZ) ? 1 : 0;
        int pix = i - g * (HSZ * HSZ);
        int hy = pix / HSZ;
        int hx = pix - hy * HSZ;
        int gy = by - 3 + hy;
        int gx = bx - 3 + hx;
        float4 v = {0.f, 0.f, 0.f, 0.f};
        if ((unsigned)gy < (unsigned)H && (unsigned)gx < (unsigned)W) {
            const float* sp = xb + (g * 4) * HW + gy * W + gx;
            v.x = sp[0]; v.y = sp[HW]; v.z = sp[2 * HW]; v.w = sp[3 * HW];
        }
        xs4[g][hy][hx] = v;
    }
    __syncthreads();

    float4 acc[2][2];  // [dy][g]
#pragma unroll
    for (int dy = 0; dy < 2; ++dy)
#pragma unroll
        for (int g = 0; g < 2; ++g) acc[dy][g] = float4{0.f, 0.f, 0.f, 0.f};

#pragma unroll
    for (int g = 0; g < 2; ++g) {
#pragma unroll
        for (int r = 0; r < 8; ++r) {        // halo row = 2*tyl + r
#pragma unroll
            for (int j = 0; j < 7; ++j) {
                const float4 v = xs4[g][2 * tyl + r][tx + j];
                if (r < 7) {                 // contributes to pixel0, i = r
                    const float wv = wreg[0][r * 7 + j];
                    acc[0][g].x = fmaf(wv, v.x, acc[0][g].x);
                    acc[0][g].y = fmaf(wv, v.y, acc[0][g].y);
                    acc[0][g].z = fmaf(wv, v.z, acc[0][g].z);
                    acc[0][g].w = fmaf(wv, v.w, acc[0][g].w);
                }
                if (r >= 1) {                // contributes to pixel1, i = r-1
                    const float wv = wreg[1][(r - 1) * 7 + j];
                    acc[1][g].x = fmaf(wv, v.x, acc[1][g].x);
                    acc[1][g].y = fmaf(wv, v.y, acc[1][g].y);
                    acc[1][g].z = fmaf(wv, v.z, acc[1][g].z);
                    acc[1][g].w = fmaf(wv, v.w, acc[1][g].w);
                }
            }
        }
    }

#pragma unroll
    for (int dy = 0; dy < 2; ++dy) {
        const int p = dy ? p1 : p0;
        if (FUSE_CONV) {
            float o0 = 0.f, o1 = 0.f, o2 = 0.f;
            const float a[8] = {acc[dy][0].x, acc[dy][0].y, acc[dy][0].z, acc[dy][0].w,
                                acc[dy][1].x, acc[dy][1].y, acc[dy][1].z, acc[dy][1].w};
#pragma unroll
            for (int k = 0; k < 8; ++k) {
                const int c = cbase + k;
                o0 = fmaf(a[k], cw[c], o0);
                o1 = fmaf(a[k], cw[NC + c], o1);
                o2 = fmaf(a[k], cw[2 * NC + c], o2);
            }
            const int z = blockIdx.z;
            y[(z * 3 + 0) * HW + p] = o0;
            y[(z * 3 + 1) * HW + p] = o1;
            y[(z * 3 + 2) * HW + p] = o2;
        } else {
            y[(cbase + 0) * HW + p] = acc[dy][0].x;
            y[(cbase + 1) * HW + p] = acc[dy][0].y;
            y[(cbase + 2) * HW + p] = acc[dy][0].z;
            y[(cbase + 3) * HW + p] = acc[dy][0].w;
            y[(cbase + 4) * HW + p] = acc[dy][1].x;
            y[(cbase + 5) * HW + p] = acc[dy][1].y;
            y[(cbase + 6) * HW + p] = acc[dy][1].z;
            y[(cbase + 7) * HW + p] = acc[dy][1].w;
        }
    }
}

// ---- fused z-reduce + bias + bilinear x4 upsample --------------------------
#define OUTS 384
#define SRCP 10
__global__ __launch_bounds__(256) void upsample_kernel(const float* __restrict__ partial,
                                                       const float* __restrict__ cb,
                                                       float* __restrict__ dst) {
    __shared__ float cvs[3][SRCP][SRCP];
    const int X = blockIdx.x * 32;
    const int Y = blockIdx.y * 32;
    const int x0s = X >> 2;
    const int y0s = Y >> 2;

    for (int e = threadIdx.x; e < 3 * SRCP * SRCP; e += 256) {
        int ch = e / (SRCP * SRCP);
        int r = e - ch * (SRCP * SRCP);
        int sy = r / SRCP;
        int sx = r - sy * SRCP;
        int gy = min(max(y0s - 1 + sy, 0), H - 1);
        int gx = min(max(x0s - 1 + sx, 0), W - 1);
        const int p = gy * W + gx;
        float sum = cb[ch];
#pragma unroll
        for (int z = 0; z < NZ; ++z) sum += partial[(z * 3 + ch) * HW + p];
        cvs[ch][sy][sx] = sum;
    }
    __syncthreads();

    const int xl = threadIdx.x & 31;
    const int yl0 = threadIdx.x >> 5;
    const int xo = X + xl;
    const float sxf = xo * 0.25f - 0.375f;
    const float fxf = floorf(sxf);
    const int jx = (int)fxf - (x0s - 1);
    const float fx = sxf - fxf;

#pragma unroll
    for (int k = 0; k < 4; ++k) {
        const int yo = Y + yl0 + 8 * k;
        const float syf = yo * 0.25f - 0.375f;
        const float fyf = floorf(syf);
        const int jy = (int)fyf - (y0s - 1);
        const float fy = syf - fyf;
#pragma unroll
        for (int ch = 0; ch < 3; ++ch) {
            const float v00 = cvs[ch][jy][jx], v01 = cvs[ch][jy][jx + 1];
            const float v10 = cvs[ch][jy + 1][jx], v11 = cvs[ch][jy + 1][jx + 1];
            const float v0 = v00 + (v01 - v00) * fx;
            const float v1 = v10 + (v11 - v10) * fx;
            dst[ch * OUTS * OUTS + yo * OUTS + xo] = v0 + (v1 - v0) * fy;
        }
    }
}

extern "C" void kernel_launch(void* const* d_in, const int* in_sizes, int n_in,
                              void* d_out, int out_size, void* d_ws, size_t ws_size,
                              hipStream_t stream) {
    const float* input  = (const float*)d_in[0];   // (1,256,96,96)
    const float* weight = (const float*)d_in[1];   // (1,49,9216)
    const float* conv_w = (const float*)d_in[2];   // (3,256)
    const float* conv_b = (const float*)d_in[3];   // (3,)
    float* out = (float*)d_out;                    // (1,3,384,384)

    float* ws = (float*)d_ws;
    float* x1      = ws;                      // 256*9216
    float* partial = x1 + NC * HW;            // 32*3*9216

    dim3 g(W / TSX, H / TSY, NZ);             // (6,6,32)
    step_kernel<0><<<g, 128, 0, stream>>>(input, weight, nullptr, x1);
    step_kernel<1><<<g, 128, 0, stream>>>(x1, weight, conv_w, partial);

    dim3 gu(OUTS / 32, OUTS / 32);            // (12,12)
    upsample_kernel<<<gu, 256, 0, stream>>>(partial, conv_b, out);
}

// Round 5
// 35.594 us; speedup vs baseline: 2.0451x; 2.0451x over previous
//
#include <hip/hip_runtime.h>

#define HW 9216
#define W 96
#define H 96
#define NC 256
#define NT 49
#define EPSV 1e-5f

#define TS 16
#define HSZ 22
#define CC 8
#define NZ (NC / CC)   // 32 z-blocks

typedef _Float16 half8 __attribute__((ext_vector_type(8)));

// ---- fused normalize + message passing step --------------------------------
// LDS: xs[hy][hx] = 8 channels packed fp16 (16 B). One ds_read_b128 per tap
// feeds 8 FMAs (fp32 accumulate, weight broadcast). 49 b128 reads per pixel.
template <int FUSE_CONV>
__global__ __launch_bounds__(256) void step_kernel(const float* __restrict__ x,
                                                   const float* __restrict__ w,
                                                   const float* __restrict__ cw,
                                                   float* __restrict__ y) {
    __shared__ half8 xs[HSZ][HSZ];  // 484*16 = 7744 B
    const int tx = threadIdx.x & 15;
    const int ty = threadIdx.x >> 4;
    const int bx = blockIdx.x * TS;
    const int by = blockIdx.y * TS;
    const int px = bx + tx;
    const int py = by + ty;
    const int p = py * W + px;

    // load + normalize the 49 per-pixel weights in registers (fp32)
    float wreg[NT];
    float s = 0.f;
#pragma unroll
    for (int t = 0; t < NT; ++t) { wreg[t] = w[t * HW + p]; s += wreg[t]; }
    const float inv = 1.f / (s + EPSV);
#pragma unroll
    for (int t = 0; t < NT; ++t) wreg[t] *= inv;

    // stage 8 channels' 22x22 halo, packed fp16 (zero-padded)
    const int cbase = blockIdx.z * CC;
    const float* __restrict__ xb = x + cbase * HW;
    for (int i = threadIdx.x; i < HSZ * HSZ; i += 256) {
        int hy = i / HSZ;
        int hx = i - hy * HSZ;
        int gy = by - 3 + hy;
        int gx = bx - 3 + hx;
        half8 h;
#pragma unroll
        for (int c = 0; c < 8; ++c) h[c] = (_Float16)0.f;
        if ((unsigned)gy < (unsigned)H && (unsigned)gx < (unsigned)W) {
            const float* sp = xb + gy * W + gx;
#pragma unroll
            for (int c = 0; c < 8; ++c) h[c] = (_Float16)sp[c * HW];
        }
        xs[hy][hx] = h;
    }
    __syncthreads();

    float acc[8];
#pragma unroll
    for (int k = 0; k < 8; ++k) acc[k] = 0.f;

#pragma unroll
    for (int i = 0; i < 7; ++i) {
#pragma unroll
        for (int j = 0; j < 7; ++j) {
            const float wv = wreg[i * 7 + j];
            const half8 v = xs[ty + i][tx + j];
#pragma unroll
            for (int k = 0; k < 8; ++k)
                acc[k] = fmaf((float)v[k], wv, acc[k]);
        }
    }

    if (FUSE_CONV) {
        float o0 = 0.f, o1 = 0.f, o2 = 0.f;
#pragma unroll
        for (int k = 0; k < 8; ++k) {
            const int c = cbase + k;
            o0 = fmaf(acc[k], cw[c], o0);
            o1 = fmaf(acc[k], cw[NC + c], o1);
            o2 = fmaf(acc[k], cw[2 * NC + c], o2);
        }
        const int z = blockIdx.z;
        y[(z * 3 + 0) * HW + p] = o0;
        y[(z * 3 + 1) * HW + p] = o1;
        y[(z * 3 + 2) * HW + p] = o2;
    } else {
#pragma unroll
        for (int k = 0; k < 8; ++k)
            y[(cbase + k) * HW + p] = acc[k];
    }
}

// ---- fused z-reduce + bias + bilinear x4 upsample --------------------------
#define OUTS 384
#define SRCP 10
__global__ __launch_bounds__(256) void upsample_kernel(const float* __restrict__ partial,
                                                       const float* __restrict__ cb,
                                                       float* __restrict__ dst) {
    __shared__ float cvs[3][SRCP][SRCP];
    const int X = blockIdx.x * 32;
    const int Y = blockIdx.y * 32;
    const int x0s = X >> 2;
    const int y0s = Y >> 2;

    for (int e = threadIdx.x; e < 3 * SRCP * SRCP; e += 256) {
        int ch = e / (SRCP * SRCP);
        int r = e - ch * (SRCP * SRCP);
        int sy = r / SRCP;
        int sx = r - sy * SRCP;
        int gy = min(max(y0s - 1 + sy, 0), H - 1);
        int gx = min(max(x0s - 1 + sx, 0), W - 1);
        const int p = gy * W + gx;
        float sum = cb[ch];
#pragma unroll
        for (int z = 0; z < NZ; ++z) sum += partial[(z * 3 + ch) * HW + p];
        cvs[ch][sy][sx] = sum;
    }
    __syncthreads();

    const int xl = threadIdx.x & 31;
    const int yl0 = threadIdx.x >> 5;
    const int xo = X + xl;
    const float sxf = xo * 0.25f - 0.375f;
    const float fxf = floorf(sxf);
    const int jx = (int)fxf - (x0s - 1);
    const float fx = sxf - fxf;

#pragma unroll
    for (int k = 0; k < 4; ++k) {
        const int yo = Y + yl0 + 8 * k;
        const float syf = yo * 0.25f - 0.375f;
        const float fyf = floorf(syf);
        const int jy = (int)fyf - (y0s - 1);
        const float fy = syf - fyf;
#pragma unroll
        for (int ch = 0; ch < 3; ++ch) {
            const float v00 = cvs[ch][jy][jx], v01 = cvs[ch][jy][jx + 1];
            const float v10 = cvs[ch][jy + 1][jx], v11 = cvs[ch][jy + 1][jx + 1];
            const float v0 = v00 + (v01 - v00) * fx;
            const float v1 = v10 + (v11 - v10) * fx;
            dst[ch * OUTS * OUTS + yo * OUTS + xo] = v0 + (v1 - v0) * fy;
        }
    }
}

extern "C" void kernel_launch(void* const* d_in, const int* in_sizes, int n_in,
                              void* d_out, int out_size, void* d_ws, size_t ws_size,
                              hipStream_t stream) {
    const float* input  = (const float*)d_in[0];   // (1,256,96,96)
    const float* weight = (const float*)d_in[1];   // (1,49,9216)
    const float* conv_w = (const float*)d_in[2];   // (3,256)
    const float* conv_b = (const float*)d_in[3];   // (3,)
    float* out = (float*)d_out;                    // (1,3,384,384)

    float* ws = (float*)d_ws;
    float* x1      = ws;                      // 256*9216
    float* partial = x1 + NC * HW;            // 32*3*9216

    dim3 g(W / TS, H / TS, NZ);               // (6,6,32)
    step_kernel<0><<<g, 256, 0, stream>>>(input, weight, nullptr, x1);
    step_kernel<1><<<g, 256, 0, stream>>>(x1, weight, conv_w, partial);

    dim3 gu(OUTS / 32, OUTS / 32);            // (12,12)
    upsample_kernel<<<gu, 256, 0, stream>>>(partial, conv_b, out);
}